// Round 14
// baseline (145.567 us; speedup 1.0000x reference)
//
#include <hip/hip_runtime.h>
#include <math.h>

// HSTU jagged attention, MFMA bf16, DMA-staged tile images, exact-LPT schedule.
// out = (silu(Q K^T) / N * mask) V, no softmax. H=8, D=DV=64, N=1024.
// Mask (exact collapse): valid(n,m) = (m < thr(n)) | (m == n),
//   thr(n) = (an>0 ? an : M) + c - 1, an = clamp(n-c+1,0,M), M = L-c+1-ncand.
// R14: R11 main kernel (256 thr, proven 42us, no spills) + invN folded into
// V tile images at prep + exact greedy-LPT over 16-block pods (R13's scheduler,
// the only good part of R13). 512-thr config abandoned (allocator spills).

#define HH      8
#define DDIM    64
#define QT      64
#define KT      64
#define STRIDE  512
#define NMAX    1024
#define NORD    16
#define TILE_HW 8192          // ushorts per tile image (16 KB)
#define NBLK    1024
#define SLOTS   10

typedef __attribute__((ext_vector_type(8))) short short8;
typedef __attribute__((ext_vector_type(4))) float f32x4;
typedef __attribute__((ext_vector_type(4))) uint  u32x4;

static __device__ __forceinline__ uint pk2(float a, float b) {
  uint r;
  asm("v_cvt_pk_bf16_f32 %0, %1, %2" : "=v"(r) : "v"(a), "v"(b));
  return r;
}

static __device__ __forceinline__ void dma16(const ushort* g, ushort* l) {
  __builtin_amdgcn_global_load_lds(
      (const __attribute__((address_space(1))) void*)g,
      (__attribute__((address_space(3))) void*)l, 16, 0, 0);
}

// ---- pre-pass: packed swizzled tile images [K 8KB | V^T/N 8KB];
//      block (0,0,0) also emits the exact-LPT schedule (16-block pods).
__global__ void build_tiles(const float* __restrict__ tk,
                            const float* __restrict__ tv,
                            ushort* __restrict__ tiles,
                            const int* __restrict__ offsets,
                            const int* __restrict__ pN,
                            short* __restrict__ sched, int Bb) {
  const int mt = blockIdx.x, h = blockIdx.y, b = blockIdx.z;
  const int off = offsets[b];
  const int L   = offsets[b + 1] - off;
  const int tid = threadIdx.x;
  const float invN = 1.0f / (float)pN[0];
  const bool sched_block = (mt == 0 && h == 0 && b == 0);

  __shared__ ushort tr[64][66];

  if (mt * 64 < L) {
    ushort* img = tiles + (size_t)((b * NORD + mt) * HH + h) * TILE_HW;
    const int row = tid >> 2;
    const int c0  = (tid & 3) * 16;
    const int m   = mt * 64 + row;
    const int sw  = (row & 7) << 3;

    // K rows -> img[0..4095] (swizzled LDS image)
    {
      uint u[8];
      if (m < L) {
        const float* s = tk + (size_t)(off + m) * STRIDE + h * DDIM + c0;
        float4 a = *(const float4*)(s),      b4 = *(const float4*)(s + 4);
        float4 c4 = *(const float4*)(s + 8), d4 = *(const float4*)(s + 12);
        u[0] = pk2(a.x, a.y);   u[1] = pk2(a.z, a.w);
        u[2] = pk2(b4.x, b4.y); u[3] = pk2(b4.z, b4.w);
        u[4] = pk2(c4.x, c4.y); u[5] = pk2(c4.z, c4.w);
        u[6] = pk2(d4.x, d4.y); u[7] = pk2(d4.z, d4.w);
      } else {
#pragma unroll
        for (int j = 0; j < 8; ++j) u[j] = 0u;
      }
      *(uint4*)&img[row * 64 + (c0 ^ sw)]       = make_uint4(u[0], u[1], u[2], u[3]);
      *(uint4*)&img[row * 64 + ((c0 + 8) ^ sw)] = make_uint4(u[4], u[5], u[6], u[7]);
    }
    // V rows (scaled by 1/N) -> LDS for transpose
    {
      uint u[8];
      if (m < L) {
        const float* s = tv + (size_t)(off + m) * STRIDE + h * DDIM + c0;
        float4 a = *(const float4*)(s),      b4 = *(const float4*)(s + 4);
        float4 c4 = *(const float4*)(s + 8), d4 = *(const float4*)(s + 12);
        u[0] = pk2(a.x * invN, a.y * invN);   u[1] = pk2(a.z * invN, a.w * invN);
        u[2] = pk2(b4.x * invN, b4.y * invN); u[3] = pk2(b4.z * invN, b4.w * invN);
        u[4] = pk2(c4.x * invN, c4.y * invN); u[5] = pk2(c4.z * invN, c4.w * invN);
        u[6] = pk2(d4.x * invN, d4.y * invN); u[7] = pk2(d4.z * invN, d4.w * invN);
      } else {
#pragma unroll
        for (int j = 0; j < 8; ++j) u[j] = 0u;
      }
#pragma unroll
      for (int j = 0; j < 8; ++j) *(uint*)&tr[row][c0 + 2 * j] = u[j];
    }
    __syncthreads();
    // V^T -> img[4096..8191]: dv=row, m-chunk=c0 (swizzled)
    {
      const int dv = tid >> 2;
      const int tc = (tid & 3) * 16;
      uint u[8];
#pragma unroll
      for (int j = 0; j < 8; ++j)
        u[j] = (uint)tr[tc + 2 * j][dv] | ((uint)tr[tc + 2 * j + 1][dv] << 16);
      *(uint4*)&img[4096 + row * 64 + (c0 ^ sw)]       = make_uint4(u[0], u[1], u[2], u[3]);
      *(uint4*)&img[4096 + row * 64 + ((c0 + 8) ^ sw)] = make_uint4(u[4], u[5], u[6], u[7]);
    }
  }

  // ---- schedule (block (0,0,0)): exact greedy LPT per (g,hh) pod, no atomics
  if (!sched_block) return;
  for (int i = tid; i < NBLK * SLOTS; i += 256) sched[i] = (short)-1;
  __syncthreads();
  if (tid < 64) {
    const int g = tid >> 3, hh = tid & 7;
    int nq[16];
    {
      int o0 = offsets[0];
      for (int bb = 0; bb < Bb; ++bb) {
        int o1 = offsets[bb + 1];
        nq[bb] = (o1 - o0 + QT - 1) / QT;
        o0 = o1;
      }
    }
    // rank batches by nq desc (stable); heavy r pairs with light Bb-1-r -> grp r%8
    int gb0 = -1, gb1 = -1;
    for (int bb = 0; bb < Bb; ++bb) {
      int r = 0;
      for (int j = 0; j < Bb; ++j)
        r += (nq[j] > nq[bb]) || (nq[j] == nq[bb] && j < bb);
      int gg = (r < Bb / 2) ? (r & 7) : ((Bb - 1 - r) & 7);
      if (gg == g) { if (r < Bb / 2) gb0 = bb; else gb1 = bb; }
    }
    // exact greedy LPT over this pod's 16 blocks (desc item cost)
    int loads[16], scnt[16];
    for (int j = 0; j < 16; ++j) { loads[j] = 0; scnt[j] = 0; }
    for (int cst = 16; cst >= 1; --cst) {
      for (int s = 0; s < 2; ++s) {
        const int bb = (s == 0) ? gb0 : gb1;
        if (bb < 0) continue;
        const int q = nq[bb];
        for (int which = 0; which < 2; ++which) {
          int qt = -1;
          if (which == 0 && cst == q) qt = 0;             // contextual full sweep
          if (which == 1 && cst >= 2 && cst <= q) qt = cst - 1;
          if (qt < 0) continue;
          // least-loaded block with a free slot
          int bj = -1;
          for (int j = 0; j < 16; ++j)
            if (scnt[j] < SLOTS && (bj < 0 || loads[j] < loads[bj])) bj = j;
          loads[bj] += cst;
          const int blk = g + 8 * (hh * 16 + bj);          // stays on XCD g
          sched[blk * SLOTS + scnt[bj]] = (short)((bb << 7) | (hh << 4) | qt);
          scnt[bj]++;
        }
      }
    }
  }
}

__global__ void zero_ctr(uint* ctr) { *ctr = 0u; }

// ---- main: DMA-staged tile images, statically scheduled (R11 structure) ----
__launch_bounds__(256, 4)
__global__ void hstu_s(const float* __restrict__ tq,
                       const ushort* __restrict__ tiles,
                       const short* __restrict__ sched,
                       const int* __restrict__ offsets,
                       const int* __restrict__ ncand,
                       const int* __restrict__ nctx,
                       float* __restrict__ out, int Tm1) {
  __shared__ ushort KV[2][TILE_HW];  // double-buffered [K 8KB | V^T 8KB]  32 KB
  __shared__ ushort Ps[4 * 1024];    // per-wave P strips                  8 KB

  const int tid  = threadIdx.x;
  const int w    = tid >> 6;
  const int lane = tid & 63;
  const int lo   = lane & 15;
  const int hi   = lane >> 4;

  ushort* Pw = &Ps[w * 1024];
  const short* my = sched + blockIdx.x * SLOTS;

  for (int slot = 0; slot < SLOTS; ++slot) {
    const int e = my[slot];
    if (e < 0) return;
    const int b = (e >> 7) & 15, h = (e >> 4) & 7, qt = e & 15;
    const int off = offsets[b];
    const int L   = offsets[b + 1] - off;
    const int n0  = qt * QT;
    if (n0 >= L) continue;

    const int c = nctx[b];
    const int M = L - c + 1 - ncand[b];
    const int m_hi  = (n0 < c) ? L : min(n0 + QT, L);
    const int niter = (m_hi + KT - 1) / KT;

    const ushort* ibase = tiles + (size_t)(b * NORD * HH + h) * TILE_HW;

    __syncthreads();                         // prev item's LDS fully consumed

    // prologue: DMA tile 0 into KV[0]
    {
      const ushort* src = ibase + w * 2048 + lane * 8;
      ushort* dst = &KV[0][w * 2048];
#pragma unroll
      for (int i = 0; i < 4; ++i) dma16(src + i * 512, dst + i * 512);
    }

    // Q -> registers (frag: q-row = n0 + w*16 + lo, k = ks*32 + hi*8 + 0..7)
    short8 qf[2];
    {
      int qr = min(off + n0 + w * 16 + lo, Tm1);
      const float* qp = tq + (size_t)qr * STRIDE + h * DDIM + hi * 8;
      float4 qa = *(const float4*)(qp);
      float4 qb = *(const float4*)(qp + 4);
      float4 qc = *(const float4*)(qp + 32);
      float4 qd = *(const float4*)(qp + 36);
      u32x4 v0 = {pk2(qa.x, qa.y), pk2(qa.z, qa.w), pk2(qb.x, qb.y), pk2(qb.z, qb.w)};
      u32x4 v1 = {pk2(qc.x, qc.y), pk2(qc.z, qc.w), pk2(qd.x, qd.y), pk2(qd.z, qd.w)};
      qf[0] = __builtin_bit_cast(short8, v0);
      qf[1] = __builtin_bit_cast(short8, v1);
    }

    // per-lane mask scalars (q-row = n): valid = nok & ((m < thr) | (m == n))
    const int  n   = n0 + w * 16 + lo;
    const int  an  = min(max(n - c + 1, 0), M);
    const int  thr = (an > 0 ? an : M) + c - 1;
    const bool nok = n < L;

    f32x4 oacc[4];
#pragma unroll
    for (int i = 0; i < 4; ++i) oacc[i] = (f32x4){0.f, 0.f, 0.f, 0.f};

    for (int t = 0; t < niter; ++t) {
      __syncthreads();   // drains tile-t DMA; gates buf (t+1)&1 reuse

      if (t + 1 < niter) {
        const ushort* src = ibase + (size_t)(t + 1) * (HH * TILE_HW)
                            + w * 2048 + lane * 8;
        ushort* dst = &KV[(t + 1) & 1][w * 2048];
#pragma unroll
        for (int i = 0; i < 4; ++i) dma16(src + i * 512, dst + i * 512);
      }

      const ushort* Kb = KV[t & 1];
      const ushort* Vb = Kb + 4096;
      const int m0 = t * KT;

      // S^T = K Q^T (swapped): lane holds P[q=lo][m = m0+kc*16+4*hi+r]
#pragma unroll
      for (int kc = 0; kc < 4; ++kc) {
        const int krw = kc * 16 + lo;
        const int ksw = (krw & 7) << 3;
        short8 kf0 = *(const short8*)&Kb[krw * 64 + ((hi * 8) ^ ksw)];
        short8 kf1 = *(const short8*)&Kb[krw * 64 + ((32 + hi * 8) ^ ksw)];
        f32x4 s4 = (f32x4){0.f, 0.f, 0.f, 0.f};
        s4 = __builtin_amdgcn_mfma_f32_16x16x32_bf16(kf0, qf[0], s4, 0, 0, 0);
        s4 = __builtin_amdgcn_mfma_f32_16x16x32_bf16(kf1, qf[1], s4, 0, 0, 0);
        const int mb = m0 + kc * 16 + 4 * hi;
        float pp[4];
#pragma unroll
        for (int r = 0; r < 4; ++r) {
          const int mm = mb + r;
          const bool valid = nok & ((mm < thr) | (mm == n));
          float s = valid ? s4[r] : 0.f;     // silu(0)=0; no NaN path
          pp[r] = s * __builtin_amdgcn_rcpf(1.f + __expf(-s));  // 1/N folded into V
        }
        const int col = kc * 16 + 4 * hi;    // 4-aligned -> 8B packed write
        *(uint2*)&Pw[lo * 64 + (col ^ ((lo & 7) << 3))] =
            make_uint2(pk2(pp[0], pp[1]), pk2(pp[2], pp[3]));
      }

      // O += P V (wave-private P round-trip, no barrier)
#pragma unroll
      for (int mc = 0; mc < 2; ++mc) {
        short8 pf = *(const short8*)&Pw[lo * 64 + ((mc * 32 + hi * 8) ^ ((lo & 7) << 3))];
#pragma unroll
        for (int dvc = 0; dvc < 4; ++dvc) {
          const int vrow = dvc * 16 + lo;
          short8 vf = *(const short8*)&Vb[vrow * 64 + ((mc * 32 + hi * 8) ^ ((vrow & 7) << 3))];
          oacc[dvc] = __builtin_amdgcn_mfma_f32_16x16x32_bf16(pf, vf, oacc[dvc], 0, 0, 0);
        }
      }
    }

    // write out (fp32), C-frag layout: row q = 4*hi+r, col dv = dvc*16+lo
#pragma unroll
    for (int dvc = 0; dvc < 4; ++dvc) {
#pragma unroll
      for (int r = 0; r < 4; ++r) {
        int nn = n0 + w * 16 + hi * 4 + r;
        if (nn < L)
          out[(size_t)(off + nn) * STRIDE + h * DDIM + dvc * 16 + lo] = oacc[dvc][r];
      }
    }
  }
}

// ---- fallback (ws too small / B>16): reg-staged fp32 queue path ----
__launch_bounds__(256)
__global__ void hstu_fb(const float* __restrict__ tq,
                        const float* __restrict__ tk,
                        const float* __restrict__ tv,
                        const int* __restrict__ offsets,
                        const int* __restrict__ pN,
                        const int* __restrict__ ncand,
                        const int* __restrict__ nctx,
                        float* __restrict__ out,
                        uint* __restrict__ ctr,
                        int Tm1, int Bb) {
  const int bhc    = Bb * HH;
  const int nitems = NORD * bhc;

  __shared__ ushort Ks[KT * DDIM];
  __shared__ ushort Vt[DDIM * KT];
  __shared__ ushort Ps[4 * 1024];
  __shared__ int s_item;

  const int tid  = threadIdx.x;
  const int w    = tid >> 6;
  const int lane = tid & 63;
  const int lo   = lane & 15;
  const int hi   = lane >> 4;
  const float invN = 1.0f / (float)pN[0];
  ushort* Pw = &Ps[w * 1024];

  for (;;) {
    __syncthreads();
    if (tid == 0) s_item = (int)atomicAdd(ctr, 1u);
    __syncthreads();
    const int item = s_item;
    if (item >= nitems) return;
    const int ord = item / bhc;
    const int rem = item - ord * bhc;
    const int b = rem / HH, h = rem - b * HH;
    const int qt = (ord == 0) ? 0 : (NORD - ord);
    const int off = offsets[b];
    const int L   = offsets[b + 1] - off;
    const int n0  = qt * QT;
    if (n0 >= L) continue;

    const int c = nctx[b];
    const int M = L - c + 1 - ncand[b];
    const int m_hi  = (n0 < c) ? L : min(n0 + QT, L);
    const int niter = (m_hi + KT - 1) / KT;

    short8 qf[2];
    {
      int qr = min(off + n0 + w * 16 + lo, Tm1);
      const float* qp = tq + (size_t)qr * STRIDE + h * DDIM + hi * 8;
      float4 qa = *(const float4*)(qp);
      float4 qb = *(const float4*)(qp + 4);
      float4 qc = *(const float4*)(qp + 32);
      float4 qd = *(const float4*)(qp + 36);
      u32x4 v0 = {pk2(qa.x, qa.y), pk2(qa.z, qa.w), pk2(qb.x, qb.y), pk2(qb.z, qb.w)};
      u32x4 v1 = {pk2(qc.x, qc.y), pk2(qc.z, qc.w), pk2(qd.x, qd.y), pk2(qd.z, qd.w)};
      qf[0] = __builtin_bit_cast(short8, v0);
      qf[1] = __builtin_bit_cast(short8, v1);
    }

    const int  n   = n0 + w * 16 + lo;
    const int  an  = min(max(n - c + 1, 0), M);
    const int  thr = (an > 0 ? an : M) + c - 1;
    const bool nok = n < L;

    f32x4 oacc[4];
#pragma unroll
    for (int i = 0; i < 4; ++i) oacc[i] = (f32x4){0.f, 0.f, 0.f, 0.f};

    for (int t = 0; t < niter; ++t) {
      const int m0 = t * KT;
      __syncthreads();
#pragma unroll
      for (int jj = 0; jj < 4; ++jj) {
        int row = (tid >> 4) + jj * 16;
        int r2  = min(off + m0 + row, Tm1);
        float4 kv = *(const float4*)(tk + (size_t)r2 * STRIDE + h * DDIM + (tid & 15) * 4);
        uint2 pk;
        pk.x = pk2(kv.x, kv.y);
        pk.y = pk2(kv.z, kv.w);
        *(uint2*)&Ks[row * 64 + (((tid & 15) * 4) ^ ((row & 7) << 3))] = pk;
      }
      {
        uint bb[8];
#pragma unroll
        for (int j = 0; j < 8; ++j) {
          int ra = min(off + m0 + w * 16 + 2 * j,     Tm1);
          int rb = min(off + m0 + w * 16 + 2 * j + 1, Tm1);
          float va = tv[(size_t)ra * STRIDE + h * DDIM + lane];
          float vb = tv[(size_t)rb * STRIDE + h * DDIM + lane];
          bb[j] = pk2(va, vb);
        }
        int s = (lane & 7) << 3;
        *(uint4*)&Vt[lane * 64 + ((w * 16)     ^ s)] = make_uint4(bb[0], bb[1], bb[2], bb[3]);
        *(uint4*)&Vt[lane * 64 + ((w * 16 + 8) ^ s)] = make_uint4(bb[4], bb[5], bb[6], bb[7]);
      }
      __syncthreads();

#pragma unroll
      for (int kc = 0; kc < 4; ++kc) {
        const int krw = kc * 16 + lo;
        const int ksw = (krw & 7) << 3;
        short8 kf0 = *(const short8*)&Ks[krw * 64 + ((hi * 8) ^ ksw)];
        short8 kf1 = *(const short8*)&Ks[krw * 64 + ((32 + hi * 8) ^ ksw)];
        f32x4 s4 = (f32x4){0.f, 0.f, 0.f, 0.f};
        s4 = __builtin_amdgcn_mfma_f32_16x16x32_bf16(kf0, qf[0], s4, 0, 0, 0);
        s4 = __builtin_amdgcn_mfma_f32_16x16x32_bf16(kf1, qf[1], s4, 0, 0, 0);
        const int mb = m0 + kc * 16 + 4 * hi;
        float pp[4];
#pragma unroll
        for (int r = 0; r < 4; ++r) {
          const int mm = mb + r;
          const bool valid = nok & ((mm < thr) | (mm == n));
          float s = valid ? s4[r] : 0.f;
          pp[r] = s * invN * __builtin_amdgcn_rcpf(1.f + __expf(-s));
        }
        const int col = kc * 16 + 4 * hi;
        *(uint2*)&Pw[lo * 64 + (col ^ ((lo & 7) << 3))] =
            make_uint2(pk2(pp[0], pp[1]), pk2(pp[2], pp[3]));
      }

#pragma unroll
      for (int mc = 0; mc < 2; ++mc) {
        short8 pf = *(const short8*)&Pw[lo * 64 + ((mc * 32 + hi * 8) ^ ((lo & 7) << 3))];
#pragma unroll
        for (int dvc = 0; dvc < 4; ++dvc) {
          const int vrow = dvc * 16 + lo;
          short8 vf = *(const short8*)&Vt[vrow * 64 + ((mc * 32 + hi * 8) ^ ((vrow & 7) << 3))];
          oacc[dvc] = __builtin_amdgcn_mfma_f32_16x16x32_bf16(pf, vf, oacc[dvc], 0, 0, 0);
        }
      }
    }

#pragma unroll
    for (int dvc = 0; dvc < 4; ++dvc) {
#pragma unroll
      for (int r = 0; r < 4; ++r) {
        int nn = n0 + w * 16 + hi * 4 + r;
        if (nn < L)
          out[(size_t)(off + nn) * STRIDE + h * DDIM + dvc * 16 + lo] = oacc[dvc][r];
      }
    }
  }
}

extern "C" void kernel_launch(void* const* d_in, const int* in_sizes, int n_in,
                              void* d_out, int out_size, void* d_ws, size_t ws_size,
                              hipStream_t stream) {
  const float* tq      = (const float*)d_in[0];
  const float* tk      = (const float*)d_in[1];
  const float* tv      = (const float*)d_in[2];
  const int*   offsets = (const int*)d_in[3];
  const int*   pN      = (const int*)d_in[4];
  const int*   ncand   = (const int*)d_in[5];
  const int*   nctx    = (const int*)d_in[6];
  float*       out     = (float*)d_out;

  const int B = in_sizes[3] - 1;
  const int T = in_sizes[0] / STRIDE;

  uint*   ctr   = (uint*)d_ws;
  short*  sched = (short*)((char*)d_ws + 256);
  ushort* tiles = (ushort*)((char*)d_ws + 256 + NBLK * SLOTS * sizeof(short));
  const size_t need = 256 + NBLK * SLOTS * sizeof(short)
                      + (size_t)B * NORD * HH * TILE_HW * sizeof(ushort);

  dim3 block(256);

  if (ws_size >= need && B <= 16) {
    dim3 tgrid(NORD, HH, B);
    build_tiles<<<tgrid, block, 0, stream>>>(tk, tv, tiles, offsets, pN, sched, B);
    hstu_s<<<NBLK, block, 0, stream>>>(tq, tiles, sched, offsets, ncand,
                                       nctx, out, T - 1);
  } else {
    zero_ctr<<<1, 1, 0, stream>>>(ctr);
    hstu_fb<<<NBLK, block, 0, stream>>>(tq, tk, tv, offsets, pN, ncand,
                                        nctx, out, ctr, T - 1, B);
  }
}

// Round 15
// 80.168 us; speedup vs baseline: 1.8158x; 1.8158x over previous
//
#include <hip/hip_runtime.h>
#include <math.h>

// HSTU jagged attention, MFMA bf16, DMA-staged tile images, exact-LPT schedule.
// out = (silu(Q K^T) / N * mask) V, no softmax. H=8, D=DV=64, N=1024.
// Mask (exact collapse): valid(n,m) = (m < thr(n)) | (m == n),
//   thr(n) = (an>0 ? an : M) + c - 1, an = clamp(n-c+1,0,M), M = L-c+1-ncand.
// R15: R14's scheduler used runtime-indexed LOCAL arrays -> scratch (rule #20):
// one block spent ~95us on scratch round-trips. Arrays moved to LDS. Main
// kernel unchanged (R11 structure + invN folded into V + exact-LPT schedule).

#define HH      8
#define DDIM    64
#define QT      64
#define KT      64
#define STRIDE  512
#define NMAX    1024
#define NORD    16
#define TILE_HW 8192          // ushorts per tile image (16 KB)
#define NBLK    1024
#define SLOTS   10

typedef __attribute__((ext_vector_type(8))) short short8;
typedef __attribute__((ext_vector_type(4))) float f32x4;
typedef __attribute__((ext_vector_type(4))) uint  u32x4;

static __device__ __forceinline__ uint pk2(float a, float b) {
  uint r;
  asm("v_cvt_pk_bf16_f32 %0, %1, %2" : "=v"(r) : "v"(a), "v"(b));
  return r;
}

static __device__ __forceinline__ void dma16(const ushort* g, ushort* l) {
  __builtin_amdgcn_global_load_lds(
      (const __attribute__((address_space(1))) void*)g,
      (__attribute__((address_space(3))) void*)l, 16, 0, 0);
}

// ---- pre-pass: packed swizzled tile images [K 8KB | V^T/N 8KB];
//      block (0,0,0) also emits the exact-LPT schedule (16-block pods).
__global__ void build_tiles(const float* __restrict__ tk,
                            const float* __restrict__ tv,
                            ushort* __restrict__ tiles,
                            const int* __restrict__ offsets,
                            const int* __restrict__ pN,
                            short* __restrict__ sched, int Bb) {
  const int mt = blockIdx.x, h = blockIdx.y, b = blockIdx.z;
  const int off = offsets[b];
  const int L   = offsets[b + 1] - off;
  const int tid = threadIdx.x;
  const float invN = 1.0f / (float)pN[0];
  const bool sched_block = (mt == 0 && h == 0 && b == 0);

  __shared__ ushort tr[64][66];
  // scheduler state in LDS (runtime-indexed arrays must NOT be thread-local:
  // scratch round-trips made R14's sched block take ~95us — rule #20)
  __shared__ int nq_sh[16];
  __shared__ int loads_s[64][17];   // padded rows: bank spread
  __shared__ int scnt_s[64][17];

  if (mt * 64 < L) {
    ushort* img = tiles + (size_t)((b * NORD + mt) * HH + h) * TILE_HW;
    const int row = tid >> 2;
    const int c0  = (tid & 3) * 16;
    const int m   = mt * 64 + row;
    const int sw  = (row & 7) << 3;

    // K rows -> img[0..4095] (swizzled LDS image)
    {
      uint u[8];
      if (m < L) {
        const float* s = tk + (size_t)(off + m) * STRIDE + h * DDIM + c0;
        float4 a = *(const float4*)(s),      b4 = *(const float4*)(s + 4);
        float4 c4 = *(const float4*)(s + 8), d4 = *(const float4*)(s + 12);
        u[0] = pk2(a.x, a.y);   u[1] = pk2(a.z, a.w);
        u[2] = pk2(b4.x, b4.y); u[3] = pk2(b4.z, b4.w);
        u[4] = pk2(c4.x, c4.y); u[5] = pk2(c4.z, c4.w);
        u[6] = pk2(d4.x, d4.y); u[7] = pk2(d4.z, d4.w);
      } else {
#pragma unroll
        for (int j = 0; j < 8; ++j) u[j] = 0u;
      }
      *(uint4*)&img[row * 64 + (c0 ^ sw)]       = make_uint4(u[0], u[1], u[2], u[3]);
      *(uint4*)&img[row * 64 + ((c0 + 8) ^ sw)] = make_uint4(u[4], u[5], u[6], u[7]);
    }
    // V rows (scaled by 1/N) -> LDS for transpose
    {
      uint u[8];
      if (m < L) {
        const float* s = tv + (size_t)(off + m) * STRIDE + h * DDIM + c0;
        float4 a = *(const float4*)(s),      b4 = *(const float4*)(s + 4);
        float4 c4 = *(const float4*)(s + 8), d4 = *(const float4*)(s + 12);
        u[0] = pk2(a.x * invN, a.y * invN);   u[1] = pk2(a.z * invN, a.w * invN);
        u[2] = pk2(b4.x * invN, b4.y * invN); u[3] = pk2(b4.z * invN, b4.w * invN);
        u[4] = pk2(c4.x * invN, c4.y * invN); u[5] = pk2(c4.z * invN, c4.w * invN);
        u[6] = pk2(d4.x * invN, d4.y * invN); u[7] = pk2(d4.z * invN, d4.w * invN);
      } else {
#pragma unroll
        for (int j = 0; j < 8; ++j) u[j] = 0u;
      }
#pragma unroll
      for (int j = 0; j < 8; ++j) *(uint*)&tr[row][c0 + 2 * j] = u[j];
    }
    __syncthreads();
    // V^T -> img[4096..8191]: dv=row, m-chunk=c0 (swizzled)
    {
      const int dv = tid >> 2;
      const int tc = (tid & 3) * 16;
      uint u[8];
#pragma unroll
      for (int j = 0; j < 8; ++j)
        u[j] = (uint)tr[tc + 2 * j][dv] | ((uint)tr[tc + 2 * j + 1][dv] << 16);
      *(uint4*)&img[4096 + row * 64 + (c0 ^ sw)]       = make_uint4(u[0], u[1], u[2], u[3]);
      *(uint4*)&img[4096 + row * 64 + ((c0 + 8) ^ sw)] = make_uint4(u[4], u[5], u[6], u[7]);
    }
  }

  // ---- schedule (block (0,0,0)): exact greedy LPT per (g,hh) pod; all state LDS
  if (!sched_block) return;
  for (int i = tid; i < NBLK * SLOTS; i += 256) sched[i] = (short)-1;
  if (tid < 16) {
    nq_sh[tid] = (tid < Bb)
        ? (offsets[tid + 1] - offsets[tid] + QT - 1) / QT : 0;
  }
  if (tid < 64) {
#pragma unroll
    for (int j = 0; j < 16; ++j) { loads_s[tid][j] = 0; scnt_s[tid][j] = 0; }
  }
  __syncthreads();
  if (tid < 64) {
    const int g = tid >> 3, hh = tid & 7;
    int* loads = loads_s[tid];
    int* scnt  = scnt_s[tid];
    // rank batches by nq desc (stable); heavy r pairs with light Bb-1-r -> grp r%8
    int gb0 = -1, gb1 = -1;
    for (int bb = 0; bb < Bb; ++bb) {
      int nqb = nq_sh[bb];
      int r = 0;
      for (int j = 0; j < 16; ++j)
        if (j < Bb) r += (nq_sh[j] > nqb) || (nq_sh[j] == nqb && j < bb);
      int gg = (r < Bb / 2) ? (r & 7) : ((Bb - 1 - r) & 7);
      if (gg == g) { if (r < Bb / 2) gb0 = bb; else gb1 = bb; }
    }
    // exact greedy LPT over this pod's 16 blocks (desc item cost)
    for (int cst = 16; cst >= 1; --cst) {
      for (int s = 0; s < 2; ++s) {
        const int bb = (s == 0) ? gb0 : gb1;
        if (bb < 0) continue;
        const int q = nq_sh[bb];
        for (int which = 0; which < 2; ++which) {
          int qt = -1;
          if (which == 0 && cst == q) qt = 0;             // contextual full sweep
          if (which == 1 && cst >= 2 && cst <= q) qt = cst - 1;
          if (qt < 0) continue;
          // least-loaded block with a free slot
          int bj = -1, bl = 0x7FFFFFFF;
          for (int j = 0; j < 16; ++j) {
            int lj = loads[j];
            bool ok = (scnt[j] < SLOTS) && (lj < bl);
            bj = ok ? j : bj;
            bl = ok ? lj : bl;
          }
          loads[bj] += cst;
          const int blk = g + 8 * (hh * 16 + bj);          // stays on XCD g
          sched[blk * SLOTS + scnt[bj]] = (short)((bb << 7) | (hh << 4) | qt);
          scnt[bj]++;
        }
      }
    }
  }
}

__global__ void zero_ctr(uint* ctr) { *ctr = 0u; }

// ---- main: DMA-staged tile images, statically scheduled (R11 structure) ----
__launch_bounds__(256, 4)
__global__ void hstu_s(const float* __restrict__ tq,
                       const ushort* __restrict__ tiles,
                       const short* __restrict__ sched,
                       const int* __restrict__ offsets,
                       const int* __restrict__ ncand,
                       const int* __restrict__ nctx,
                       float* __restrict__ out, int Tm1) {
  __shared__ ushort KV[2][TILE_HW];  // double-buffered [K 8KB | V^T 8KB]  32 KB
  __shared__ ushort Ps[4 * 1024];    // per-wave P strips                  8 KB

  const int tid  = threadIdx.x;
  const int w    = tid >> 6;
  const int lane = tid & 63;
  const int lo   = lane & 15;
  const int hi   = lane >> 4;

  ushort* Pw = &Ps[w * 1024];
  const short* my = sched + blockIdx.x * SLOTS;

  for (int slot = 0; slot < SLOTS; ++slot) {
    const int e = my[slot];
    if (e < 0) return;
    const int b = (e >> 7) & 15, h = (e >> 4) & 7, qt = e & 15;
    const int off = offsets[b];
    const int L   = offsets[b + 1] - off;
    const int n0  = qt * QT;
    if (n0 >= L) continue;

    const int c = nctx[b];
    const int M = L - c + 1 - ncand[b];
    const int m_hi  = (n0 < c) ? L : min(n0 + QT, L);
    const int niter = (m_hi + KT - 1) / KT;

    const ushort* ibase = tiles + (size_t)(b * NORD * HH + h) * TILE_HW;

    __syncthreads();                         // prev item's LDS fully consumed

    // prologue: DMA tile 0 into KV[0]
    {
      const ushort* src = ibase + w * 2048 + lane * 8;
      ushort* dst = &KV[0][w * 2048];
#pragma unroll
      for (int i = 0; i < 4; ++i) dma16(src + i * 512, dst + i * 512);
    }

    // Q -> registers (frag: q-row = n0 + w*16 + lo, k = ks*32 + hi*8 + 0..7)
    short8 qf[2];
    {
      int qr = min(off + n0 + w * 16 + lo, Tm1);
      const float* qp = tq + (size_t)qr * STRIDE + h * DDIM + hi * 8;
      float4 qa = *(const float4*)(qp);
      float4 qb = *(const float4*)(qp + 4);
      float4 qc = *(const float4*)(qp + 32);
      float4 qd = *(const float4*)(qp + 36);
      u32x4 v0 = {pk2(qa.x, qa.y), pk2(qa.z, qa.w), pk2(qb.x, qb.y), pk2(qb.z, qb.w)};
      u32x4 v1 = {pk2(qc.x, qc.y), pk2(qc.z, qc.w), pk2(qd.x, qd.y), pk2(qd.z, qd.w)};
      qf[0] = __builtin_bit_cast(short8, v0);
      qf[1] = __builtin_bit_cast(short8, v1);
    }

    // per-lane mask scalars (q-row = n): valid = nok & ((m < thr) | (m == n))
    const int  n   = n0 + w * 16 + lo;
    const int  an  = min(max(n - c + 1, 0), M);
    const int  thr = (an > 0 ? an : M) + c - 1;
    const bool nok = n < L;

    f32x4 oacc[4];
#pragma unroll
    for (int i = 0; i < 4; ++i) oacc[i] = (f32x4){0.f, 0.f, 0.f, 0.f};

    for (int t = 0; t < niter; ++t) {
      __syncthreads();   // drains tile-t DMA; gates buf (t+1)&1 reuse

      if (t + 1 < niter) {
        const ushort* src = ibase + (size_t)(t + 1) * (HH * TILE_HW)
                            + w * 2048 + lane * 8;
        ushort* dst = &KV[(t + 1) & 1][w * 2048];
#pragma unroll
        for (int i = 0; i < 4; ++i) dma16(src + i * 512, dst + i * 512);
      }

      const ushort* Kb = KV[t & 1];
      const ushort* Vb = Kb + 4096;
      const int m0 = t * KT;

      // S^T = K Q^T (swapped): lane holds P[q=lo][m = m0+kc*16+4*hi+r]
#pragma unroll
      for (int kc = 0; kc < 4; ++kc) {
        const int krw = kc * 16 + lo;
        const int ksw = (krw & 7) << 3;
        short8 kf0 = *(const short8*)&Kb[krw * 64 + ((hi * 8) ^ ksw)];
        short8 kf1 = *(const short8*)&Kb[krw * 64 + ((32 + hi * 8) ^ ksw)];
        f32x4 s4 = (f32x4){0.f, 0.f, 0.f, 0.f};
        s4 = __builtin_amdgcn_mfma_f32_16x16x32_bf16(kf0, qf[0], s4, 0, 0, 0);
        s4 = __builtin_amdgcn_mfma_f32_16x16x32_bf16(kf1, qf[1], s4, 0, 0, 0);
        const int mb = m0 + kc * 16 + 4 * hi;
        float pp[4];
#pragma unroll
        for (int r = 0; r < 4; ++r) {
          const int mm = mb + r;
          const bool valid = nok & ((mm < thr) | (mm == n));
          float s = valid ? s4[r] : 0.f;     // silu(0)=0; no NaN path
          pp[r] = s * __builtin_amdgcn_rcpf(1.f + __expf(-s));  // 1/N folded into V
        }
        const int col = kc * 16 + 4 * hi;    // 4-aligned -> 8B packed write
        *(uint2*)&Pw[lo * 64 + (col ^ ((lo & 7) << 3))] =
            make_uint2(pk2(pp[0], pp[1]), pk2(pp[2], pp[3]));
      }

      // O += P V (wave-private P round-trip, no barrier)
#pragma unroll
      for (int mc = 0; mc < 2; ++mc) {
        short8 pf = *(const short8*)&Pw[lo * 64 + ((mc * 32 + hi * 8) ^ ((lo & 7) << 3))];
#pragma unroll
        for (int dvc = 0; dvc < 4; ++dvc) {
          const int vrow = dvc * 16 + lo;
          short8 vf = *(const short8*)&Vb[vrow * 64 + ((mc * 32 + hi * 8) ^ ((vrow & 7) << 3))];
          oacc[dvc] = __builtin_amdgcn_mfma_f32_16x16x32_bf16(pf, vf, oacc[dvc], 0, 0, 0);
        }
      }
    }

    // write out (fp32), C-frag layout: row q = 4*hi+r, col dv = dvc*16+lo
#pragma unroll
    for (int dvc = 0; dvc < 4; ++dvc) {
#pragma unroll
      for (int r = 0; r < 4; ++r) {
        int nn = n0 + w * 16 + hi * 4 + r;
        if (nn < L)
          out[(size_t)(off + nn) * STRIDE + h * DDIM + dvc * 16 + lo] = oacc[dvc][r];
      }
    }
  }
}

// ---- fallback (ws too small / B>16): reg-staged fp32 queue path ----
__launch_bounds__(256)
__global__ void hstu_fb(const float* __restrict__ tq,
                        const float* __restrict__ tk,
                        const float* __restrict__ tv,
                        const int* __restrict__ offsets,
                        const int* __restrict__ pN,
                        const int* __restrict__ ncand,
                        const int* __restrict__ nctx,
                        float* __restrict__ out,
                        uint* __restrict__ ctr,
                        int Tm1, int Bb) {
  const int bhc    = Bb * HH;
  const int nitems = NORD * bhc;

  __shared__ ushort Ks[KT * DDIM];
  __shared__ ushort Vt[DDIM * KT];
  __shared__ ushort Ps[4 * 1024];
  __shared__ int s_item;

  const int tid  = threadIdx.x;
  const int w    = tid >> 6;
  const int lane = tid & 63;
  const int lo   = lane & 15;
  const int hi   = lane >> 4;
  const float invN = 1.0f / (float)pN[0];
  ushort* Pw = &Ps[w * 1024];

  for (;;) {
    __syncthreads();
    if (tid == 0) s_item = (int)atomicAdd(ctr, 1u);
    __syncthreads();
    const int item = s_item;
    if (item >= nitems) return;
    const int ord = item / bhc;
    const int rem = item - ord * bhc;
    const int b = rem / HH, h = rem - b * HH;
    const int qt = (ord == 0) ? 0 : (NORD - ord);
    const int off = offsets[b];
    const int L   = offsets[b + 1] - off;
    const int n0  = qt * QT;
    if (n0 >= L) continue;

    const int c = nctx[b];
    const int M = L - c + 1 - ncand[b];
    const int m_hi  = (n0 < c) ? L : min(n0 + QT, L);
    const int niter = (m_hi + KT - 1) / KT;

    short8 qf[2];
    {
      int qr = min(off + n0 + w * 16 + lo, Tm1);
      const float* qp = tq + (size_t)qr * STRIDE + h * DDIM + hi * 8;
      float4 qa = *(const float4*)(qp);
      float4 qb = *(const float4*)(qp + 4);
      float4 qc = *(const float4*)(qp + 32);
      float4 qd = *(const float4*)(qp + 36);
      u32x4 v0 = {pk2(qa.x, qa.y), pk2(qa.z, qa.w), pk2(qb.x, qb.y), pk2(qb.z, qb.w)};
      u32x4 v1 = {pk2(qc.x, qc.y), pk2(qc.z, qc.w), pk2(qd.x, qd.y), pk2(qd.z, qd.w)};
      qf[0] = __builtin_bit_cast(short8, v0);
      qf[1] = __builtin_bit_cast(short8, v1);
    }

    const int  n   = n0 + w * 16 + lo;
    const int  an  = min(max(n - c + 1, 0), M);
    const int  thr = (an > 0 ? an : M) + c - 1;
    const bool nok = n < L;

    f32x4 oacc[4];
#pragma unroll
    for (int i = 0; i < 4; ++i) oacc[i] = (f32x4){0.f, 0.f, 0.f, 0.f};

    for (int t = 0; t < niter; ++t) {
      const int m0 = t * KT;
      __syncthreads();
#pragma unroll
      for (int jj = 0; jj < 4; ++jj) {
        int row = (tid >> 4) + jj * 16;
        int r2  = min(off + m0 + row, Tm1);
        float4 kv = *(const float4*)(tk + (size_t)r2 * STRIDE + h * DDIM + (tid & 15) * 4);
        uint2 pk;
        pk.x = pk2(kv.x, kv.y);
        pk.y = pk2(kv.z, kv.w);
        *(uint2*)&Ks[row * 64 + (((tid & 15) * 4) ^ ((row & 7) << 3))] = pk;
      }
      {
        uint bb[8];
#pragma unroll
        for (int j = 0; j < 8; ++j) {
          int ra = min(off + m0 + w * 16 + 2 * j,     Tm1);
          int rb = min(off + m0 + w * 16 + 2 * j + 1, Tm1);
          float va = tv[(size_t)ra * STRIDE + h * DDIM + lane];
          float vb = tv[(size_t)rb * STRIDE + h * DDIM + lane];
          bb[j] = pk2(va, vb);
        }
        int s = (lane & 7) << 3;
        *(uint4*)&Vt[lane * 64 + ((w * 16)     ^ s)] = make_uint4(bb[0], bb[1], bb[2], bb[3]);
        *(uint4*)&Vt[lane * 64 + ((w * 16 + 8) ^ s)] = make_uint4(bb[4], bb[5], bb[6], bb[7]);
      }
      __syncthreads();

#pragma unroll
      for (int kc = 0; kc < 4; ++kc) {
        const int krw = kc * 16 + lo;
        const int ksw = (krw & 7) << 3;
        short8 kf0 = *(const short8*)&Ks[krw * 64 + ((hi * 8) ^ ksw)];
        short8 kf1 = *(const short8*)&Ks[krw * 64 + ((32 + hi * 8) ^ ksw)];
        f32x4 s4 = (f32x4){0.f, 0.f, 0.f, 0.f};
        s4 = __builtin_amdgcn_mfma_f32_16x16x32_bf16(kf0, qf[0], s4, 0, 0, 0);
        s4 = __builtin_amdgcn_mfma_f32_16x16x32_bf16(kf1, qf[1], s4, 0, 0, 0);
        const int mb = m0 + kc * 16 + 4 * hi;
        float pp[4];
#pragma unroll
        for (int r = 0; r < 4; ++r) {
          const int mm = mb + r;
          const bool valid = nok & ((mm < thr) | (mm == n));
          float s = valid ? s4[r] : 0.f;
          pp[r] = s * invN * __builtin_amdgcn_rcpf(1.f + __expf(-s));
        }
        const int col = kc * 16 + 4 * hi;
        *(uint2*)&Pw[lo * 64 + (col ^ ((lo & 7) << 3))] =
            make_uint2(pk2(pp[0], pp[1]), pk2(pp[2], pp[3]));
      }

#pragma unroll
      for (int mc = 0; mc < 2; ++mc) {
        short8 pf = *(const short8*)&Pw[lo * 64 + ((mc * 32 + hi * 8) ^ ((lo & 7) << 3))];
#pragma unroll
        for (int dvc = 0; dvc < 4; ++dvc) {
          const int vrow = dvc * 16 + lo;
          short8 vf = *(const short8*)&Vt[vrow * 64 + ((mc * 32 + hi * 8) ^ ((vrow & 7) << 3))];
          oacc[dvc] = __builtin_amdgcn_mfma_f32_16x16x32_bf16(pf, vf, oacc[dvc], 0, 0, 0);
        }
      }
    }

#pragma unroll
    for (int dvc = 0; dvc < 4; ++dvc) {
#pragma unroll
      for (int r = 0; r < 4; ++r) {
        int nn = n0 + w * 16 + hi * 4 + r;
        if (nn < L)
          out[(size_t)(off + nn) * STRIDE + h * DDIM + dvc * 16 + lo] = oacc[dvc][r];
      }
    }
  }
}

extern "C" void kernel_launch(void* const* d_in, const int* in_sizes, int n_in,
                              void* d_out, int out_size, void* d_ws, size_t ws_size,
                              hipStream_t stream) {
  const float* tq      = (const float*)d_in[0];
  const float* tk      = (const float*)d_in[1];
  const float* tv      = (const float*)d_in[2];
  const int*   offsets = (const int*)d_in[3];
  const int*   pN      = (const int*)d_in[4];
  const int*   ncand   = (const int*)d_in[5];
  const int*   nctx    = (const int*)d_in[6];
  float*       out     = (float*)d_out;

  const int B = in_sizes[3] - 1;
  const int T = in_sizes[0] / STRIDE;

  uint*   ctr   = (uint*)d_ws;
  short*  sched = (short*)((char*)d_ws + 256);
  ushort* tiles = (ushort*)((char*)d_ws + 256 + NBLK * SLOTS * sizeof(short));
  const size_t need = 256 + NBLK * SLOTS * sizeof(short)
                      + (size_t)B * NORD * HH * TILE_HW * sizeof(ushort);

  dim3 block(256);

  if (ws_size >= need && B <= 16) {
    dim3 tgrid(NORD, HH, B);
    build_tiles<<<tgrid, block, 0, stream>>>(tk, tv, tiles, offsets, pN, sched, B);
    hstu_s<<<NBLK, block, 0, stream>>>(tq, tiles, sched, offsets, ncand,
                                       nctx, out, T - 1);
  } else {
    zero_ctr<<<1, 1, 0, stream>>>(ctr);
    hstu_fb<<<NBLK, block, 0, stream>>>(tq, tk, tv, offsets, pN, ncand,
                                        nctx, out, ctr, T - 1, B);
  }
}

// Round 16
// 62.647 us; speedup vs baseline: 2.3236x; 1.2797x over previous
//
#include <hip/hip_runtime.h>
#include <math.h>

// HSTU jagged attention, MFMA bf16, DMA-staged tile images, SELF-SCHEDULED.
// out = (silu(Q K^T) / N * mask) V, no softmax. H=8, D=DV=64, N=1024.
// Mask (exact collapse): valid(n,m) = (m < thr(n)) | (m == n),
//   thr(n) = (an>0 ? an : M) + c - 1, an = clamp(n-c+1,0,M), M = L-c+1-ncand.
// R16: scheduler ELIMINATED. The R11 snake schedule is a closed-form function
// of (blockIdx, nq[]): rank r=i*8+h is owned by block lb=r (slot0) if r<128
// else lb=255-r (slot1) within XCD-group g=blk&7. Each block derives its own
// <=2 items inline (~60 ALU iters, parallel across blocks). Prep = pure tile
// building. Main kernel = R11 structure (proven 42us) + invN folded into V.

#define HH      8
#define DDIM    64
#define QT      64
#define KT      64
#define STRIDE  512
#define NMAX    1024
#define NORD    16
#define TILE_HW 8192          // ushorts per tile image (16 KB)
#define NBLK    1024

typedef __attribute__((ext_vector_type(8))) short short8;
typedef __attribute__((ext_vector_type(4))) float f32x4;
typedef __attribute__((ext_vector_type(4))) uint  u32x4;

static __device__ __forceinline__ uint pk2(float a, float b) {
  uint r;
  asm("v_cvt_pk_bf16_f32 %0, %1, %2" : "=v"(r) : "v"(a), "v"(b));
  return r;
}

static __device__ __forceinline__ void dma16(const ushort* g, ushort* l) {
  __builtin_amdgcn_global_load_lds(
      (const __attribute__((address_space(1))) void*)g,
      (__attribute__((address_space(3))) void*)l, 16, 0, 0);
}

// ---- pre-pass: packed swizzled tile images [K 8KB | (V/N)^T 8KB]. ----
__global__ void build_tiles(const float* __restrict__ tk,
                            const float* __restrict__ tv,
                            ushort* __restrict__ tiles,
                            const int* __restrict__ offsets,
                            const int* __restrict__ pN) {
  const int mt = blockIdx.x, h = blockIdx.y, b = blockIdx.z;
  const int off = offsets[b];
  const int L   = offsets[b + 1] - off;
  if (mt * 64 >= L) return;
  const int tid = threadIdx.x;
  const float invN = 1.0f / (float)pN[0];

  __shared__ ushort tr[64][66];

  ushort* img = tiles + (size_t)((b * NORD + mt) * HH + h) * TILE_HW;
  const int row = tid >> 2;
  const int c0  = (tid & 3) * 16;
  const int m   = mt * 64 + row;
  const int sw  = (row & 7) << 3;

  // K rows -> img[0..4095] (swizzled LDS image)
  {
    uint u[8];
    if (m < L) {
      const float* s = tk + (size_t)(off + m) * STRIDE + h * DDIM + c0;
      float4 a = *(const float4*)(s),      b4 = *(const float4*)(s + 4);
      float4 c4 = *(const float4*)(s + 8), d4 = *(const float4*)(s + 12);
      u[0] = pk2(a.x, a.y);   u[1] = pk2(a.z, a.w);
      u[2] = pk2(b4.x, b4.y); u[3] = pk2(b4.z, b4.w);
      u[4] = pk2(c4.x, c4.y); u[5] = pk2(c4.z, c4.w);
      u[6] = pk2(d4.x, d4.y); u[7] = pk2(d4.z, d4.w);
    } else {
#pragma unroll
      for (int j = 0; j < 8; ++j) u[j] = 0u;
    }
    *(uint4*)&img[row * 64 + (c0 ^ sw)]       = make_uint4(u[0], u[1], u[2], u[3]);
    *(uint4*)&img[row * 64 + ((c0 + 8) ^ sw)] = make_uint4(u[4], u[5], u[6], u[7]);
  }
  // V rows (scaled by 1/N) -> LDS for transpose
  {
    uint u[8];
    if (m < L) {
      const float* s = tv + (size_t)(off + m) * STRIDE + h * DDIM + c0;
      float4 a = *(const float4*)(s),      b4 = *(const float4*)(s + 4);
      float4 c4 = *(const float4*)(s + 8), d4 = *(const float4*)(s + 12);
      u[0] = pk2(a.x * invN, a.y * invN);   u[1] = pk2(a.z * invN, a.w * invN);
      u[2] = pk2(b4.x * invN, b4.y * invN); u[3] = pk2(b4.z * invN, b4.w * invN);
      u[4] = pk2(c4.x * invN, c4.y * invN); u[5] = pk2(c4.z * invN, c4.w * invN);
      u[6] = pk2(d4.x * invN, d4.y * invN); u[7] = pk2(d4.z * invN, d4.w * invN);
    } else {
#pragma unroll
      for (int j = 0; j < 8; ++j) u[j] = 0u;
    }
#pragma unroll
    for (int j = 0; j < 8; ++j) *(uint*)&tr[row][c0 + 2 * j] = u[j];
  }
  __syncthreads();
  // V^T -> img[4096..8191]: dv=row, m-chunk=c0 (swizzled)
  {
    const int dv = tid >> 2;
    const int tc = (tid & 3) * 16;
    uint u[8];
#pragma unroll
    for (int j = 0; j < 8; ++j)
      u[j] = (uint)tr[tc + 2 * j][dv] | ((uint)tr[tc + 2 * j + 1][dv] << 16);
    *(uint4*)&img[4096 + row * 64 + (c0 ^ sw)]       = make_uint4(u[0], u[1], u[2], u[3]);
    *(uint4*)&img[4096 + row * 64 + ((c0 + 8) ^ sw)] = make_uint4(u[4], u[5], u[6], u[7]);
  }
}

__global__ void zero_ctr(uint* ctr) { *ctr = 0u; }

// ---- main: DMA-staged tile images, SELF-SCHEDULED (closed-form snake) ----
__launch_bounds__(256, 4)
__global__ void hstu_s(const float* __restrict__ tq,
                       const ushort* __restrict__ tiles,
                       const int* __restrict__ offsets,
                       const int* __restrict__ ncand,
                       const int* __restrict__ nctx,
                       float* __restrict__ out, int Tm1, int Bb) {
  __shared__ ushort KV[2][TILE_HW];  // double-buffered [K 8KB | V^T 8KB]  32 KB
  __shared__ ushort Ps[4 * 1024];    // per-wave P strips; head = sched scratch

  const int tid  = threadIdx.x;
  const int w    = tid >> 6;
  const int lane = tid & 63;
  const int lo   = lane & 15;
  const int hi   = lane >> 4;

  // ---- derive this block's items (R11 snake schedule, closed form).
  // Scratch lives in Ps (read out to registers before any P write).
  int* scr = (int*)Ps;                 // scr[0..15]=nq, scr[16..17]=items, [18]=cnt
  if (tid < 16)
    scr[tid] = (tid < Bb) ? (offsets[tid + 1] - offsets[tid] + QT - 1) / QT : 0;
  __syncthreads();
  if (tid == 0) {
    const int g = blockIdx.x & 7, lb = blockIdx.x >> 3;
    // pair batches: rank by nq desc (stable); heavy r & light Bb-1-r -> group r%8
    int gb0 = -1, gb1 = -1;
    for (int bb = 0; bb < Bb; ++bb) {
      const int nqb = scr[bb];
      int r = 0;
      for (int j = 0; j < 16; ++j)
        if (j < Bb) r += (scr[j] > nqb) || (scr[j] == nqb && j < bb);
      const int gg = (r < Bb / 2) ? (r & 7) : ((Bb - 1 - r) & 7);
      if (gg == g) { if (r < Bb / 2) gb0 = bb; else gb1 = bb; }
    }
    // enumeration index targets: rank r=i*8+h owned by lb=r (slot0) / lb=255-r
    const int i0 = lb >> 3,         h0 = lb & 7;          // i0 in [0,15]
    const int i1 = (255 - lb) >> 3, h1 = (255 - lb) & 7;  // i1 in [16,31]
    int cnt = 0, i = 0;
    int e0 = -1, e1 = -1;
    for (int cst = 16; cst >= 1; --cst) {
      for (int s = 0; s < 2; ++s) {
        const int bb = (s == 0) ? gb0 : gb1;
        if (bb < 0) continue;
        const int q = scr[bb];
        for (int which = 0; which < 2; ++which) {
          int qt = -1;
          if (which == 0 && cst == q) qt = 0;              // contextual full sweep
          if (which == 1 && cst >= 2 && cst <= q) qt = cst - 1;
          if (qt < 0) continue;
          const int enc = (bb << 7) | 0 | qt;              // h patched below
          if (i == i0) { e0 = enc | (h0 << 4); ++cnt; }
          if (i == i1) { e1 = enc | (h1 << 4); ++cnt; }
          ++i;
        }
      }
    }
    if (e0 < 0) { e0 = e1; e1 = -1; }                      // compact
    scr[16] = e0; scr[17] = e1; scr[18] = cnt;
  }
  __syncthreads();
  const int e0  = scr[16];
  const int e1  = scr[17];
  const int cnt = scr[18];
  if (cnt == 0) return;

  ushort* Pw = &Ps[w * 1024];

  for (int it = 0; it < cnt; ++it) {
    const int e = (it == 0) ? e0 : e1;
    if (e < 0) return;
    const int b = (e >> 7) & 15, h = (e >> 4) & 7, qt = e & 15;
    const int off = offsets[b];
    const int L   = offsets[b + 1] - off;
    const int n0  = qt * QT;
    if (n0 >= L) continue;

    const int c = nctx[b];
    const int M = L - c + 1 - ncand[b];
    const int m_hi  = (n0 < c) ? L : min(n0 + QT, L);
    const int niter = (m_hi + KT - 1) / KT;

    const ushort* ibase = tiles + (size_t)(b * NORD * HH + h) * TILE_HW;

    __syncthreads();                         // prev item's LDS fully consumed

    // prologue: DMA tile 0 into KV[0]
    {
      const ushort* src = ibase + w * 2048 + lane * 8;
      ushort* dst = &KV[0][w * 2048];
#pragma unroll
      for (int i2 = 0; i2 < 4; ++i2) dma16(src + i2 * 512, dst + i2 * 512);
    }

    // Q -> registers (frag: q-row = n0 + w*16 + lo, k = ks*32 + hi*8 + 0..7)
    short8 qf[2];
    {
      int qr = min(off + n0 + w * 16 + lo, Tm1);
      const float* qp = tq + (size_t)qr * STRIDE + h * DDIM + hi * 8;
      float4 qa = *(const float4*)(qp);
      float4 qb = *(const float4*)(qp + 4);
      float4 qc = *(const float4*)(qp + 32);
      float4 qd = *(const float4*)(qp + 36);
      u32x4 v0 = {pk2(qa.x, qa.y), pk2(qa.z, qa.w), pk2(qb.x, qb.y), pk2(qb.z, qb.w)};
      u32x4 v1 = {pk2(qc.x, qc.y), pk2(qc.z, qc.w), pk2(qd.x, qd.y), pk2(qd.z, qd.w)};
      qf[0] = __builtin_bit_cast(short8, v0);
      qf[1] = __builtin_bit_cast(short8, v1);
    }

    // per-lane mask scalars (q-row = n): valid = nok & ((m < thr) | (m == n))
    const int  n   = n0 + w * 16 + lo;
    const int  an  = min(max(n - c + 1, 0), M);
    const int  thr = (an > 0 ? an : M) + c - 1;
    const bool nok = n < L;

    f32x4 oacc[4];
#pragma unroll
    for (int i2 = 0; i2 < 4; ++i2) oacc[i2] = (f32x4){0.f, 0.f, 0.f, 0.f};

    for (int t = 0; t < niter; ++t) {
      __syncthreads();   // drains tile-t DMA; gates buf (t+1)&1 reuse

      if (t + 1 < niter) {
        const ushort* src = ibase + (size_t)(t + 1) * (HH * TILE_HW)
                            + w * 2048 + lane * 8;
        ushort* dst = &KV[(t + 1) & 1][w * 2048];
#pragma unroll
        for (int i2 = 0; i2 < 4; ++i2) dma16(src + i2 * 512, dst + i2 * 512);
      }

      const ushort* Kb = KV[t & 1];
      const ushort* Vb = Kb + 4096;
      const int m0 = t * KT;

      // S^T = K Q^T (swapped): lane holds P[q=lo][m = m0+kc*16+4*hi+r]
#pragma unroll
      for (int kc = 0; kc < 4; ++kc) {
        const int krw = kc * 16 + lo;
        const int ksw = (krw & 7) << 3;
        short8 kf0 = *(const short8*)&Kb[krw * 64 + ((hi * 8) ^ ksw)];
        short8 kf1 = *(const short8*)&Kb[krw * 64 + ((32 + hi * 8) ^ ksw)];
        f32x4 s4 = (f32x4){0.f, 0.f, 0.f, 0.f};
        s4 = __builtin_amdgcn_mfma_f32_16x16x32_bf16(kf0, qf[0], s4, 0, 0, 0);
        s4 = __builtin_amdgcn_mfma_f32_16x16x32_bf16(kf1, qf[1], s4, 0, 0, 0);
        const int mb = m0 + kc * 16 + 4 * hi;
        float pp[4];
#pragma unroll
        for (int r = 0; r < 4; ++r) {
          const int mm = mb + r;
          const bool valid = nok & ((mm < thr) | (mm == n));
          float s = valid ? s4[r] : 0.f;     // silu(0)=0; no NaN path
          pp[r] = s * __builtin_amdgcn_rcpf(1.f + __expf(-s));  // 1/N folded into V
        }
        const int col = kc * 16 + 4 * hi;    // 4-aligned -> 8B packed write
        *(uint2*)&Pw[lo * 64 + (col ^ ((lo & 7) << 3))] =
            make_uint2(pk2(pp[0], pp[1]), pk2(pp[2], pp[3]));
      }

      // O += P V (wave-private P round-trip, no barrier)
#pragma unroll
      for (int mc = 0; mc < 2; ++mc) {
        short8 pf = *(const short8*)&Pw[lo * 64 + ((mc * 32 + hi * 8) ^ ((lo & 7) << 3))];
#pragma unroll
        for (int dvc = 0; dvc < 4; ++dvc) {
          const int vrow = dvc * 16 + lo;
          short8 vf = *(const short8*)&Vb[vrow * 64 + ((mc * 32 + hi * 8) ^ ((vrow & 7) << 3))];
          oacc[dvc] = __builtin_amdgcn_mfma_f32_16x16x32_bf16(pf, vf, oacc[dvc], 0, 0, 0);
        }
      }
    }

    // write out (fp32), C-frag layout: row q = 4*hi+r, col dv = dvc*16+lo
#pragma unroll
    for (int dvc = 0; dvc < 4; ++dvc) {
#pragma unroll
      for (int r = 0; r < 4; ++r) {
        int nn = n0 + w * 16 + hi * 4 + r;
        if (nn < L)
          out[(size_t)(off + nn) * STRIDE + h * DDIM + dvc * 16 + lo] = oacc[dvc][r];
      }
    }
  }
}

// ---- fallback (ws too small / B>16): reg-staged fp32 queue path ----
__launch_bounds__(256)
__global__ void hstu_fb(const float* __restrict__ tq,
                        const float* __restrict__ tk,
                        const float* __restrict__ tv,
                        const int* __restrict__ offsets,
                        const int* __restrict__ pN,
                        const int* __restrict__ ncand,
                        const int* __restrict__ nctx,
                        float* __restrict__ out,
                        uint* __restrict__ ctr,
                        int Tm1, int Bb) {
  const int bhc    = Bb * HH;
  const int nitems = NORD * bhc;

  __shared__ ushort Ks[KT * DDIM];
  __shared__ ushort Vt[DDIM * KT];
  __shared__ ushort Ps[4 * 1024];
  __shared__ int s_item;

  const int tid  = threadIdx.x;
  const int w    = tid >> 6;
  const int lane = tid & 63;
  const int lo   = lane & 15;
  const int hi   = lane >> 4;
  const float invN = 1.0f / (float)pN[0];
  ushort* Pw = &Ps[w * 1024];

  for (;;) {
    __syncthreads();
    if (tid == 0) s_item = (int)atomicAdd(ctr, 1u);
    __syncthreads();
    const int item = s_item;
    if (item >= nitems) return;
    const int ord = item / bhc;
    const int rem = item - ord * bhc;
    const int b = rem / HH, h = rem - b * HH;
    const int qt = (ord == 0) ? 0 : (NORD - ord);
    const int off = offsets[b];
    const int L   = offsets[b + 1] - off;
    const int n0  = qt * QT;
    if (n0 >= L) continue;

    const int c = nctx[b];
    const int M = L - c + 1 - ncand[b];
    const int m_hi  = (n0 < c) ? L : min(n0 + QT, L);
    const int niter = (m_hi + KT - 1) / KT;

    short8 qf[2];
    {
      int qr = min(off + n0 + w * 16 + lo, Tm1);
      const float* qp = tq + (size_t)qr * STRIDE + h * DDIM + hi * 8;
      float4 qa = *(const float4*)(qp);
      float4 qb = *(const float4*)(qp + 4);
      float4 qc = *(const float4*)(qp + 32);
      float4 qd = *(const float4*)(qp + 36);
      u32x4 v0 = {pk2(qa.x, qa.y), pk2(qa.z, qa.w), pk2(qb.x, qb.y), pk2(qb.z, qb.w)};
      u32x4 v1 = {pk2(qc.x, qc.y), pk2(qc.z, qc.w), pk2(qd.x, qd.y), pk2(qd.z, qd.w)};
      qf[0] = __builtin_bit_cast(short8, v0);
      qf[1] = __builtin_bit_cast(short8, v1);
    }

    const int  n   = n0 + w * 16 + lo;
    const int  an  = min(max(n - c + 1, 0), M);
    const int  thr = (an > 0 ? an : M) + c - 1;
    const bool nok = n < L;

    f32x4 oacc[4];
#pragma unroll
    for (int i = 0; i < 4; ++i) oacc[i] = (f32x4){0.f, 0.f, 0.f, 0.f};

    for (int t = 0; t < niter; ++t) {
      const int m0 = t * KT;
      __syncthreads();
#pragma unroll
      for (int jj = 0; jj < 4; ++jj) {
        int row = (tid >> 4) + jj * 16;
        int r2  = min(off + m0 + row, Tm1);
        float4 kv = *(const float4*)(tk + (size_t)r2 * STRIDE + h * DDIM + (tid & 15) * 4);
        uint2 pk;
        pk.x = pk2(kv.x, kv.y);
        pk.y = pk2(kv.z, kv.w);
        *(uint2*)&Ks[row * 64 + (((tid & 15) * 4) ^ ((row & 7) << 3))] = pk;
      }
      {
        uint bb[8];
#pragma unroll
        for (int j = 0; j < 8; ++j) {
          int ra = min(off + m0 + w * 16 + 2 * j,     Tm1);
          int rb = min(off + m0 + w * 16 + 2 * j + 1, Tm1);
          float va = tv[(size_t)ra * STRIDE + h * DDIM + lane];
          float vb = tv[(size_t)rb * STRIDE + h * DDIM + lane];
          bb[j] = pk2(va, vb);
        }
        int s = (lane & 7) << 3;
        *(uint4*)&Vt[lane * 64 + ((w * 16)     ^ s)] = make_uint4(bb[0], bb[1], bb[2], bb[3]);
        *(uint4*)&Vt[lane * 64 + ((w * 16 + 8) ^ s)] = make_uint4(bb[4], bb[5], bb[6], bb[7]);
      }
      __syncthreads();

#pragma unroll
      for (int kc = 0; kc < 4; ++kc) {
        const int krw = kc * 16 + lo;
        const int ksw = (krw & 7) << 3;
        short8 kf0 = *(const short8*)&Ks[krw * 64 + ((hi * 8) ^ ksw)];
        short8 kf1 = *(const short8*)&Ks[krw * 64 + ((32 + hi * 8) ^ ksw)];
        f32x4 s4 = (f32x4){0.f, 0.f, 0.f, 0.f};
        s4 = __builtin_amdgcn_mfma_f32_16x16x32_bf16(kf0, qf[0], s4, 0, 0, 0);
        s4 = __builtin_amdgcn_mfma_f32_16x16x32_bf16(kf1, qf[1], s4, 0, 0, 0);
        const int mb = m0 + kc * 16 + 4 * hi;
        float pp[4];
#pragma unroll
        for (int r = 0; r < 4; ++r) {
          const int mm = mb + r;
          const bool valid = nok & ((mm < thr) | (mm == n));
          float s = valid ? s4[r] : 0.f;
          pp[r] = s * invN * __builtin_amdgcn_rcpf(1.f + __expf(-s));
        }
        const int col = kc * 16 + 4 * hi;
        *(uint2*)&Pw[lo * 64 + (col ^ ((lo & 7) << 3))] =
            make_uint2(pk2(pp[0], pp[1]), pk2(pp[2], pp[3]));
      }

#pragma unroll
      for (int mc = 0; mc < 2; ++mc) {
        short8 pf = *(const short8*)&Pw[lo * 64 + ((mc * 32 + hi * 8) ^ ((lo & 7) << 3))];
#pragma unroll
        for (int dvc = 0; dvc < 4; ++dvc) {
          const int vrow = dvc * 16 + lo;
          short8 vf = *(const short8*)&Vt[vrow * 64 + ((mc * 32 + hi * 8) ^ ((vrow & 7) << 3))];
          oacc[dvc] = __builtin_amdgcn_mfma_f32_16x16x32_bf16(pf, vf, oacc[dvc], 0, 0, 0);
        }
      }
    }

#pragma unroll
    for (int dvc = 0; dvc < 4; ++dvc) {
#pragma unroll
      for (int r = 0; r < 4; ++r) {
        int nn = n0 + w * 16 + hi * 4 + r;
        if (nn < L)
          out[(size_t)(off + nn) * STRIDE + h * DDIM + dvc * 16 + lo] = oacc[dvc][r];
      }
    }
  }
}

extern "C" void kernel_launch(void* const* d_in, const int* in_sizes, int n_in,
                              void* d_out, int out_size, void* d_ws, size_t ws_size,
                              hipStream_t stream) {
  const float* tq      = (const float*)d_in[0];
  const float* tk      = (const float*)d_in[1];
  const float* tv      = (const float*)d_in[2];
  const int*   offsets = (const int*)d_in[3];
  const int*   pN      = (const int*)d_in[4];
  const int*   ncand   = (const int*)d_in[5];
  const int*   nctx    = (const int*)d_in[6];
  float*       out     = (float*)d_out;

  const int B = in_sizes[3] - 1;
  const int T = in_sizes[0] / STRIDE;

  uint*   ctr   = (uint*)d_ws;
  ushort* tiles = (ushort*)((char*)d_ws + 256);
  const size_t need = 256 + (size_t)B * NORD * HH * TILE_HW * sizeof(ushort);

  dim3 block(256);

  if (ws_size >= need && B <= 16) {
    dim3 tgrid(NORD, HH, B);
    build_tiles<<<tgrid, block, 0, stream>>>(tk, tv, tiles, offsets, pN);
    hstu_s<<<NBLK, block, 0, stream>>>(tq, tiles, offsets, ncand, nctx, out,
                                       T - 1, B);
  } else {
    zero_ctr<<<1, 1, 0, stream>>>(ctr);
    hstu_fb<<<NBLK, block, 0, stream>>>(tq, tk, tv, offsets, pN, ncand,
                                        nctx, out, ctr, T - 1, B);
  }
}

// Round 17
// 54.508 us; speedup vs baseline: 2.6706x; 1.1493x over previous
//
#include <hip/hip_runtime.h>
#include <math.h>

// HSTU jagged attention, MFMA bf16, DMA-staged tile images, SELF-SCHEDULED.
// out = (silu(Q K^T) / N * mask) V, no softmax. H=8, D=DV=64, N=1024.
// Mask (exact collapse): valid(n,m) = (m < thr(n)) | (m == n),
//   thr(n) = (an>0 ? an : M) + c - 1, an = clamp(n-c+1,0,M), M = L-c+1-ncand.
// R17: R16's inline snake-schedule derivation had a serial tid0 ranking loop
// (256 runtime-guarded LDS reads ~13us/block). Now: 16 threads rank batches in
// parallel (race-free permutation), tid0 does a 64-iter pure-ALU enumeration.
// Everything else identical to R16 (R11-proven inner loop + invN-folded V).

#define HH      8
#define DDIM    64
#define QT      64
#define KT      64
#define STRIDE  512
#define NMAX    1024
#define NORD    16
#define TILE_HW 8192          // ushorts per tile image (16 KB)
#define NBLK    1024

typedef __attribute__((ext_vector_type(8))) short short8;
typedef __attribute__((ext_vector_type(4))) float f32x4;
typedef __attribute__((ext_vector_type(4))) uint  u32x4;

static __device__ __forceinline__ uint pk2(float a, float b) {
  uint r;
  asm("v_cvt_pk_bf16_f32 %0, %1, %2" : "=v"(r) : "v"(a), "v"(b));
  return r;
}

static __device__ __forceinline__ void dma16(const ushort* g, ushort* l) {
  __builtin_amdgcn_global_load_lds(
      (const __attribute__((address_space(1))) void*)g,
      (__attribute__((address_space(3))) void*)l, 16, 0, 0);
}

// ---- pre-pass: packed swizzled tile images [K 8KB | (V/N)^T 8KB]. ----
__global__ void build_tiles(const float* __restrict__ tk,
                            const float* __restrict__ tv,
                            ushort* __restrict__ tiles,
                            const int* __restrict__ offsets,
                            const int* __restrict__ pN) {
  const int mt = blockIdx.x, h = blockIdx.y, b = blockIdx.z;
  const int off = offsets[b];
  const int L   = offsets[b + 1] - off;
  if (mt * 64 >= L) return;
  const int tid = threadIdx.x;
  const float invN = 1.0f / (float)pN[0];

  __shared__ ushort tr[64][66];

  ushort* img = tiles + (size_t)((b * NORD + mt) * HH + h) * TILE_HW;
  const int row = tid >> 2;
  const int c0  = (tid & 3) * 16;
  const int m   = mt * 64 + row;
  const int sw  = (row & 7) << 3;

  // K rows -> img[0..4095] (swizzled LDS image)
  {
    uint u[8];
    if (m < L) {
      const float* s = tk + (size_t)(off + m) * STRIDE + h * DDIM + c0;
      float4 a = *(const float4*)(s),      b4 = *(const float4*)(s + 4);
      float4 c4 = *(const float4*)(s + 8), d4 = *(const float4*)(s + 12);
      u[0] = pk2(a.x, a.y);   u[1] = pk2(a.z, a.w);
      u[2] = pk2(b4.x, b4.y); u[3] = pk2(b4.z, b4.w);
      u[4] = pk2(c4.x, c4.y); u[5] = pk2(c4.z, c4.w);
      u[6] = pk2(d4.x, d4.y); u[7] = pk2(d4.z, d4.w);
    } else {
#pragma unroll
      for (int j = 0; j < 8; ++j) u[j] = 0u;
    }
    *(uint4*)&img[row * 64 + (c0 ^ sw)]       = make_uint4(u[0], u[1], u[2], u[3]);
    *(uint4*)&img[row * 64 + ((c0 + 8) ^ sw)] = make_uint4(u[4], u[5], u[6], u[7]);
  }
  // V rows (scaled by 1/N) -> LDS for transpose
  {
    uint u[8];
    if (m < L) {
      const float* s = tv + (size_t)(off + m) * STRIDE + h * DDIM + c0;
      float4 a = *(const float4*)(s),      b4 = *(const float4*)(s + 4);
      float4 c4 = *(const float4*)(s + 8), d4 = *(const float4*)(s + 12);
      u[0] = pk2(a.x * invN, a.y * invN);   u[1] = pk2(a.z * invN, a.w * invN);
      u[2] = pk2(b4.x * invN, b4.y * invN); u[3] = pk2(b4.z * invN, b4.w * invN);
      u[4] = pk2(c4.x * invN, c4.y * invN); u[5] = pk2(c4.z * invN, c4.w * invN);
      u[6] = pk2(d4.x * invN, d4.y * invN); u[7] = pk2(d4.z * invN, d4.w * invN);
    } else {
#pragma unroll
      for (int j = 0; j < 8; ++j) u[j] = 0u;
    }
#pragma unroll
    for (int j = 0; j < 8; ++j) *(uint*)&tr[row][c0 + 2 * j] = u[j];
  }
  __syncthreads();
  // V^T -> img[4096..8191]: dv=row, m-chunk=c0 (swizzled)
  {
    const int dv = tid >> 2;
    const int tc = (tid & 3) * 16;
    uint u[8];
#pragma unroll
    for (int j = 0; j < 8; ++j)
      u[j] = (uint)tr[tc + 2 * j][dv] | ((uint)tr[tc + 2 * j + 1][dv] << 16);
    *(uint4*)&img[4096 + row * 64 + (c0 ^ sw)]       = make_uint4(u[0], u[1], u[2], u[3]);
    *(uint4*)&img[4096 + row * 64 + ((c0 + 8) ^ sw)] = make_uint4(u[4], u[5], u[6], u[7]);
  }
}

__global__ void zero_ctr(uint* ctr) { *ctr = 0u; }

// ---- main: DMA-staged tile images, self-scheduled (parallel derivation) ----
__launch_bounds__(256, 4)
__global__ void hstu_s(const float* __restrict__ tq,
                       const ushort* __restrict__ tiles,
                       const int* __restrict__ offsets,
                       const int* __restrict__ ncand,
                       const int* __restrict__ nctx,
                       float* __restrict__ out, int Tm1, int Bb) {
  __shared__ ushort KV[2][TILE_HW];  // double-buffered [K 8KB | V^T 8KB]  32 KB
  __shared__ ushort Ps[4 * 1024];    // per-wave P strips; head = sched scratch

  const int tid  = threadIdx.x;
  const int w    = tid >> 6;
  const int lane = tid & 63;
  const int lo   = lane & 15;
  const int hi   = lane >> 4;

  // ---- derive this block's items (R11 snake, closed form), PARALLEL ranking.
  // scr[0..15]=nq, scr[16..23]=gb0 per group, scr[24..31]=gb1, scr[32..34]=out
  int* scr = (int*)Ps;
  if (tid < 16)
    scr[tid] = (tid < Bb) ? (offsets[tid + 1] - offsets[tid] + QT - 1) / QT : 0;
  if (tid >= 16 && tid < 32) scr[tid] = -1;
  __syncthreads();
  if (tid < Bb) {
    // rank tid's batch by nq desc (stable) — 16 threads in parallel
    const int nqb = scr[tid];
    int r = 0;
#pragma unroll
    for (int j = 0; j < 16; ++j) {
      int v = scr[j];
      r += (j < Bb) & ((v > nqb) | ((v == nqb) & (j < tid)));
    }
    // heavy r<Bb/2 -> gb0 of group r&7; light -> gb1 of group (Bb-1-r)&7.
    // r is a permutation => each slot written exactly once.
    if (r < Bb / 2) scr[16 + (r & 7)] = tid;
    else            scr[24 + ((Bb - 1 - r) & 7)] = tid;
  }
  __syncthreads();
  if (tid == 0) {
    const int g = blockIdx.x & 7, lb = blockIdx.x >> 3;
    const int gb0 = scr[16 + g], gb1 = scr[24 + g];
    const int q0 = (gb0 >= 0) ? scr[gb0] : -1;
    const int q1 = (gb1 >= 0) ? scr[gb1] : -1;
    const int i0 = lb >> 3,         h0 = lb & 7;
    const int i1 = (255 - lb) >> 3, h1 = (255 - lb) & 7;
    int cnt = 0, i = 0, e0 = -1, e1 = -1;
#pragma unroll
    for (int cst = 16; cst >= 1; --cst) {
#pragma unroll
      for (int s = 0; s < 2; ++s) {
        const int bb = (s == 0) ? gb0 : gb1;
        const int q  = (s == 0) ? q0 : q1;
        if (bb < 0) continue;
#pragma unroll
        for (int which = 0; which < 2; ++which) {
          int qt = -1;
          if (which == 0 && cst == q) qt = 0;              // contextual full sweep
          if (which == 1 && cst >= 2 && cst <= q) qt = cst - 1;
          if (qt < 0) continue;
          const int enc = (bb << 7) | qt;
          if (i == i0) { e0 = enc | (h0 << 4); ++cnt; }
          if (i == i1) { e1 = enc | (h1 << 4); ++cnt; }
          ++i;
        }
      }
    }
    if (e0 < 0) { e0 = e1; e1 = -1; }
    scr[32] = e0; scr[33] = e1; scr[34] = cnt;
  }
  __syncthreads();
  const int e0  = scr[32];
  const int e1  = scr[33];
  const int cnt = scr[34];
  if (cnt == 0) return;

  ushort* Pw = &Ps[w * 1024];

  for (int it = 0; it < cnt; ++it) {
    const int e = (it == 0) ? e0 : e1;
    if (e < 0) return;
    const int b = (e >> 7) & 15, h = (e >> 4) & 7, qt = e & 15;
    const int off = offsets[b];
    const int L   = offsets[b + 1] - off;
    const int n0  = qt * QT;
    if (n0 >= L) continue;

    const int c = nctx[b];
    const int M = L - c + 1 - ncand[b];
    const int m_hi  = (n0 < c) ? L : min(n0 + QT, L);
    const int niter = (m_hi + KT - 1) / KT;

    const ushort* ibase = tiles + (size_t)(b * NORD * HH + h) * TILE_HW;

    __syncthreads();                         // prev item's LDS fully consumed

    // prologue: DMA tile 0 into KV[0]
    {
      const ushort* src = ibase + w * 2048 + lane * 8;
      ushort* dst = &KV[0][w * 2048];
#pragma unroll
      for (int i2 = 0; i2 < 4; ++i2) dma16(src + i2 * 512, dst + i2 * 512);
    }

    // Q -> registers (frag: q-row = n0 + w*16 + lo, k = ks*32 + hi*8 + 0..7)
    short8 qf[2];
    {
      int qr = min(off + n0 + w * 16 + lo, Tm1);
      const float* qp = tq + (size_t)qr * STRIDE + h * DDIM + hi * 8;
      float4 qa = *(const float4*)(qp);
      float4 qb = *(const float4*)(qp + 4);
      float4 qc = *(const float4*)(qp + 32);
      float4 qd = *(const float4*)(qp + 36);
      u32x4 v0 = {pk2(qa.x, qa.y), pk2(qa.z, qa.w), pk2(qb.x, qb.y), pk2(qb.z, qb.w)};
      u32x4 v1 = {pk2(qc.x, qc.y), pk2(qc.z, qc.w), pk2(qd.x, qd.y), pk2(qd.z, qd.w)};
      qf[0] = __builtin_bit_cast(short8, v0);
      qf[1] = __builtin_bit_cast(short8, v1);
    }

    // per-lane mask scalars (q-row = n): valid = nok & ((m < thr) | (m == n))
    const int  n   = n0 + w * 16 + lo;
    const int  an  = min(max(n - c + 1, 0), M);
    const int  thr = (an > 0 ? an : M) + c - 1;
    const bool nok = n < L;

    f32x4 oacc[4];
#pragma unroll
    for (int i2 = 0; i2 < 4; ++i2) oacc[i2] = (f32x4){0.f, 0.f, 0.f, 0.f};

    for (int t = 0; t < niter; ++t) {
      __syncthreads();   // drains tile-t DMA; gates buf (t+1)&1 reuse

      if (t + 1 < niter) {
        const ushort* src = ibase + (size_t)(t + 1) * (HH * TILE_HW)
                            + w * 2048 + lane * 8;
        ushort* dst = &KV[(t + 1) & 1][w * 2048];
#pragma unroll
        for (int i2 = 0; i2 < 4; ++i2) dma16(src + i2 * 512, dst + i2 * 512);
      }

      const ushort* Kb = KV[t & 1];
      const ushort* Vb = Kb + 4096;
      const int m0 = t * KT;

      // S^T = K Q^T (swapped): lane holds P[q=lo][m = m0+kc*16+4*hi+r]
#pragma unroll
      for (int kc = 0; kc < 4; ++kc) {
        const int krw = kc * 16 + lo;
        const int ksw = (krw & 7) << 3;
        short8 kf0 = *(const short8*)&Kb[krw * 64 + ((hi * 8) ^ ksw)];
        short8 kf1 = *(const short8*)&Kb[krw * 64 + ((32 + hi * 8) ^ ksw)];
        f32x4 s4 = (f32x4){0.f, 0.f, 0.f, 0.f};
        s4 = __builtin_amdgcn_mfma_f32_16x16x32_bf16(kf0, qf[0], s4, 0, 0, 0);
        s4 = __builtin_amdgcn_mfma_f32_16x16x32_bf16(kf1, qf[1], s4, 0, 0, 0);
        const int mb = m0 + kc * 16 + 4 * hi;
        float pp[4];
#pragma unroll
        for (int r = 0; r < 4; ++r) {
          const int mm = mb + r;
          const bool valid = nok & ((mm < thr) | (mm == n));
          float s = valid ? s4[r] : 0.f;     // silu(0)=0; no NaN path
          pp[r] = s * __builtin_amdgcn_rcpf(1.f + __expf(-s));  // 1/N folded into V
        }
        const int col = kc * 16 + 4 * hi;    // 4-aligned -> 8B packed write
        *(uint2*)&Pw[lo * 64 + (col ^ ((lo & 7) << 3))] =
            make_uint2(pk2(pp[0], pp[1]), pk2(pp[2], pp[3]));
      }

      // O += P V (wave-private P round-trip, no barrier)
#pragma unroll
      for (int mc = 0; mc < 2; ++mc) {
        short8 pf = *(const short8*)&Pw[lo * 64 + ((mc * 32 + hi * 8) ^ ((lo & 7) << 3))];
#pragma unroll
        for (int dvc = 0; dvc < 4; ++dvc) {
          const int vrow = dvc * 16 + lo;
          short8 vf = *(const short8*)&Vb[vrow * 64 + ((mc * 32 + hi * 8) ^ ((vrow & 7) << 3))];
          oacc[dvc] = __builtin_amdgcn_mfma_f32_16x16x32_bf16(pf, vf, oacc[dvc], 0, 0, 0);
        }
      }
    }

    // write out (fp32), C-frag layout: row q = 4*hi+r, col dv = dvc*16+lo
#pragma unroll
    for (int dvc = 0; dvc < 4; ++dvc) {
#pragma unroll
      for (int r = 0; r < 4; ++r) {
        int nn = n0 + w * 16 + hi * 4 + r;
        if (nn < L)
          out[(size_t)(off + nn) * STRIDE + h * DDIM + dvc * 16 + lo] = oacc[dvc][r];
      }
    }
  }
}

// ---- fallback (ws too small / B>16): reg-staged fp32 queue path ----
__launch_bounds__(256)
__global__ void hstu_fb(const float* __restrict__ tq,
                        const float* __restrict__ tk,
                        const float* __restrict__ tv,
                        const int* __restrict__ offsets,
                        const int* __restrict__ pN,
                        const int* __restrict__ ncand,
                        const int* __restrict__ nctx,
                        float* __restrict__ out,
                        uint* __restrict__ ctr,
                        int Tm1, int Bb) {
  const int bhc    = Bb * HH;
  const int nitems = NORD * bhc;

  __shared__ ushort Ks[KT * DDIM];
  __shared__ ushort Vt[DDIM * KT];
  __shared__ ushort Ps[4 * 1024];
  __shared__ int s_item;

  const int tid  = threadIdx.x;
  const int w    = tid >> 6;
  const int lane = tid & 63;
  const int lo   = lane & 15;
  const int hi   = lane >> 4;
  const float invN = 1.0f / (float)pN[0];
  ushort* Pw = &Ps[w * 1024];

  for (;;) {
    __syncthreads();
    if (tid == 0) s_item = (int)atomicAdd(ctr, 1u);
    __syncthreads();
    const int item = s_item;
    if (item >= nitems) return;
    const int ord = item / bhc;
    const int rem = item - ord * bhc;
    const int b = rem / HH, h = rem - b * HH;
    const int qt = (ord == 0) ? 0 : (NORD - ord);
    const int off = offsets[b];
    const int L   = offsets[b + 1] - off;
    const int n0  = qt * QT;
    if (n0 >= L) continue;

    const int c = nctx[b];
    const int M = L - c + 1 - ncand[b];
    const int m_hi  = (n0 < c) ? L : min(n0 + QT, L);
    const int niter = (m_hi + KT - 1) / KT;

    short8 qf[2];
    {
      int qr = min(off + n0 + w * 16 + lo, Tm1);
      const float* qp = tq + (size_t)qr * STRIDE + h * DDIM + hi * 8;
      float4 qa = *(const float4*)(qp);
      float4 qb = *(const float4*)(qp + 4);
      float4 qc = *(const float4*)(qp + 32);
      float4 qd = *(const float4*)(qp + 36);
      u32x4 v0 = {pk2(qa.x, qa.y), pk2(qa.z, qa.w), pk2(qb.x, qb.y), pk2(qb.z, qb.w)};
      u32x4 v1 = {pk2(qc.x, qc.y), pk2(qc.z, qc.w), pk2(qd.x, qd.y), pk2(qd.z, qd.w)};
      qf[0] = __builtin_bit_cast(short8, v0);
      qf[1] = __builtin_bit_cast(short8, v1);
    }

    const int  n   = n0 + w * 16 + lo;
    const int  an  = min(max(n - c + 1, 0), M);
    const int  thr = (an > 0 ? an : M) + c - 1;
    const bool nok = n < L;

    f32x4 oacc[4];
#pragma unroll
    for (int i = 0; i < 4; ++i) oacc[i] = (f32x4){0.f, 0.f, 0.f, 0.f};

    for (int t = 0; t < niter; ++t) {
      const int m0 = t * KT;
      __syncthreads();
#pragma unroll
      for (int jj = 0; jj < 4; ++jj) {
        int row = (tid >> 4) + jj * 16;
        int r2  = min(off + m0 + row, Tm1);
        float4 kv = *(const float4*)(tk + (size_t)r2 * STRIDE + h * DDIM + (tid & 15) * 4);
        uint2 pk;
        pk.x = pk2(kv.x, kv.y);
        pk.y = pk2(kv.z, kv.w);
        *(uint2*)&Ks[row * 64 + (((tid & 15) * 4) ^ ((row & 7) << 3))] = pk;
      }
      {
        uint bb[8];
#pragma unroll
        for (int j = 0; j < 8; ++j) {
          int ra = min(off + m0 + w * 16 + 2 * j,     Tm1);
          int rb = min(off + m0 + w * 16 + 2 * j + 1, Tm1);
          float va = tv[(size_t)ra * STRIDE + h * DDIM + lane];
          float vb = tv[(size_t)rb * STRIDE + h * DDIM + lane];
          bb[j] = pk2(va, vb);
        }
        int s = (lane & 7) << 3;
        *(uint4*)&Vt[lane * 64 + ((w * 16)     ^ s)] = make_uint4(bb[0], bb[1], bb[2], bb[3]);
        *(uint4*)&Vt[lane * 64 + ((w * 16 + 8) ^ s)] = make_uint4(bb[4], bb[5], bb[6], bb[7]);
      }
      __syncthreads();

#pragma unroll
      for (int kc = 0; kc < 4; ++kc) {
        const int krw = kc * 16 + lo;
        const int ksw = (krw & 7) << 3;
        short8 kf0 = *(const short8*)&Ks[krw * 64 + ((hi * 8) ^ ksw)];
        short8 kf1 = *(const short8*)&Ks[krw * 64 + ((32 + hi * 8) ^ ksw)];
        f32x4 s4 = (f32x4){0.f, 0.f, 0.f, 0.f};
        s4 = __builtin_amdgcn_mfma_f32_16x16x32_bf16(kf0, qf[0], s4, 0, 0, 0);
        s4 = __builtin_amdgcn_mfma_f32_16x16x32_bf16(kf1, qf[1], s4, 0, 0, 0);
        const int mb = m0 + kc * 16 + 4 * hi;
        float pp[4];
#pragma unroll
        for (int r = 0; r < 4; ++r) {
          const int mm = mb + r;
          const bool valid = nok & ((mm < thr) | (mm == n));
          float s = valid ? s4[r] : 0.f;
          pp[r] = s * invN * __builtin_amdgcn_rcpf(1.f + __expf(-s));
        }
        const int col = kc * 16 + 4 * hi;
        *(uint2*)&Pw[lo * 64 + (col ^ ((lo & 7) << 3))] =
            make_uint2(pk2(pp[0], pp[1]), pk2(pp[2], pp[3]));
      }

#pragma unroll
      for (int mc = 0; mc < 2; ++mc) {
        short8 pf = *(const short8*)&Pw[lo * 64 + ((mc * 32 + hi * 8) ^ ((lo & 7) << 3))];
#pragma unroll
        for (int dvc = 0; dvc < 4; ++dvc) {
          const int vrow = dvc * 16 + lo;
          short8 vf = *(const short8*)&Vt[vrow * 64 + ((mc * 32 + hi * 8) ^ ((vrow & 7) << 3))];
          oacc[dvc] = __builtin_amdgcn_mfma_f32_16x16x32_bf16(pf, vf, oacc[dvc], 0, 0, 0);
        }
      }
    }

#pragma unroll
    for (int dvc = 0; dvc < 4; ++dvc) {
#pragma unroll
      for (int r = 0; r < 4; ++r) {
        int nn = n0 + w * 16 + hi * 4 + r;
        if (nn < L)
          out[(size_t)(off + nn) * STRIDE + h * DDIM + dvc * 16 + lo] = oacc[dvc][r];
      }
    }
  }
}

extern "C" void kernel_launch(void* const* d_in, const int* in_sizes, int n_in,
                              void* d_out, int out_size, void* d_ws, size_t ws_size,
                              hipStream_t stream) {
  const float* tq      = (const float*)d_in[0];
  const float* tk      = (const float*)d_in[1];
  const float* tv      = (const float*)d_in[2];
  const int*   offsets = (const int*)d_in[3];
  const int*   pN      = (const int*)d_in[4];
  const int*   ncand   = (const int*)d_in[5];
  const int*   nctx    = (const int*)d_in[6];
  float*       out     = (float*)d_out;

  const int B = in_sizes[3] - 1;
  const int T = in_sizes[0] / STRIDE;

  uint*   ctr   = (uint*)d_ws;
  ushort* tiles = (ushort*)((char*)d_ws + 256);
  const size_t need = 256 + (size_t)B * NORD * HH * TILE_HW * sizeof(ushort);

  dim3 block(256);

  if (ws_size >= need && B <= 16) {
    dim3 tgrid(NORD, HH, B);
    build_tiles<<<tgrid, block, 0, stream>>>(tk, tv, tiles, offsets, pN);
    hstu_s<<<NBLK, block, 0, stream>>>(tq, tiles, offsets, ncand, nctx, out,
                                       T - 1, B);
  } else {
    zero_ctr<<<1, 1, 0, stream>>>(ctr);
    hstu_fb<<<NBLK, block, 0, stream>>>(tq, tk, tv, offsets, pN, ncand,
                                        nctx, out, ctr, T - 1, B);
  }
}